// Round 6
// baseline (43829.532 us; speedup 1.0000x reference)
//
#include <hip/hip_runtime.h>

namespace {

constexpr int NB  = 64;    // batch
constexpr int NN  = 50;    // nodes
constexpr int DM  = 128;   // model dim
constexpr int FFDIM = 512;
constexpr int NHD = 8;     // heads
constexpr int HDM = 16;    // head dim
constexpr int KA  = 15;    // action_k
constexpr int KS  = 35;    // state_k
constexpr int TA  = 16;    // KA+1 tokens (encoder A)
constexpr int TS  = 37;    // KS+2 tokens (encoder S)
constexpr int NT  = 1024;  // threads per block
constexpr float BIGF = 1000000000.0f;

// dynamic LDS (floats)
constexpr int OFF_HA  = 0;                 // 16*128 = 2048
constexpr int OFF_HS  = 2048;              // 37*128 = 4736
constexpr int OFF_SCR = 6784;              // shared scratch
constexpr int SCR_FLOATS = 28416;          // max(attnS 25160, ffS 28416, decoder ~14k)
constexpr int SMEM_FLOATS = OFF_SCR + SCR_FLOATS;   // 35200
constexpr int SMEM_BYTES  = SMEM_FLOATS * 4;        // 140800 B

struct Params {
  const float* x; const int* start;
  const float* a_emb_W; const float* a_emb_b;
  const float* a_attn_W; const float* a_attn_b;
  const float* a_ff_W1; const float* a_ff_b1;
  const float* a_ff_W2; const float* a_ff_b2;
  const float* a_ln;
  const float* s_emb_W; const float* s_emb_b;
  const float* s_attn_W; const float* s_attn_b;
  const float* s_ff_W1; const float* s_ff_b1;
  const float* s_ff_W2; const float* s_ff_b2;
  const float* s_ln;
  const float* WK; const float* bK;
  const float* WV; const float* bV;
  const float* Wq_mlp; const float* bq_mlp;
  const float* d_Wq; const float* d_bq;
  const float* d_Wo; const float* d_bo;
  float* out;   // f32: tours (64x50) ++ logp (64)
};

template<int R>
__device__ inline void fma4(float4* acc, const float* __restrict__ in, const int* ro, int kb,
                            float4 w0, float4 w1, float4 w2, float4 w3)
{
#pragma unroll
  for (int i = 0; i < R; ++i) {
    float4 a = *(const float4*)(in + ro[i] + kb);
    acc[i].x = fmaf(a.x,w0.x,acc[i].x); acc[i].y = fmaf(a.x,w0.y,acc[i].y);
    acc[i].z = fmaf(a.x,w0.z,acc[i].z); acc[i].w = fmaf(a.x,w0.w,acc[i].w);
    acc[i].x = fmaf(a.y,w1.x,acc[i].x); acc[i].y = fmaf(a.y,w1.y,acc[i].y);
    acc[i].z = fmaf(a.y,w1.z,acc[i].z); acc[i].w = fmaf(a.y,w1.w,acc[i].w);
    acc[i].x = fmaf(a.z,w2.x,acc[i].x); acc[i].y = fmaf(a.z,w2.y,acc[i].y);
    acc[i].z = fmaf(a.z,w2.z,acc[i].z); acc[i].w = fmaf(a.z,w2.w,acc[i].w);
    acc[i].x = fmaf(a.w,w3.x,acc[i].x); acc[i].y = fmaf(a.w,w3.y,acc[i].y);
    acc[i].z = fmaf(a.w,w3.z,acc[i].z); acc[i].w = fmaf(a.w,w3.w,acc[i].w);
  }
}

// out[T x NM*128] = in[T x K] @ W + bias. NM fused 128-col blocks (block m: W + m*wBlk,
// bias + m*128, out + m*outBlk). Thread (of [tid0, tid0+NG*NM*32)) owns 4 cols x R rows.
// Redundancy per weight = NG (= ceil(T/R)). 2-stage prefetched K-loop (4-k chunks).
// bias==nullptr -> zero init. No barriers inside.
template<int R, int NG, int NM, int K>
__device__ inline void matmul_blk(const float* __restrict__ in, int lda,
                                  const float* __restrict__ W, int ldw, int wBlk,
                                  const float* __restrict__ bias,
                                  float* __restrict__ out, int ldo, int outBlk,
                                  int T, bool relu, int tid, int tid0)
{
  constexpr int NACT = NG * NM * 32;
  const int t = tid - tid0;
  if (t < 0 || t >= NACT) return;
  const int cw = t % (NM * 32);
  const int g  = t / (NM * 32);
  const int m  = cw >> 5;
  const int c  = (cw & 31) << 2;
  const float* __restrict__ wp = W + (size_t)m * wBlk + c;
  float* __restrict__ op = out + (size_t)m * outBlk + c;
  const int rb = g * R;
  int ro[R];
#pragma unroll
  for (int i = 0; i < R; ++i) ro[i] = min(rb + i, T - 1) * lda;
  float4 acc[R];
  if (bias) {
    const float4 bv4 = *(const float4*)(bias + m * 128 + c);
#pragma unroll
    for (int i = 0; i < R; ++i) acc[i] = bv4;
  } else {
#pragma unroll
    for (int i = 0; i < R; ++i) acc[i] = make_float4(0.f, 0.f, 0.f, 0.f);
  }
  float4 wA0, wA1, wA2, wA3, wB0, wB1, wB2, wB3;
  wA0 = *(const float4*)(wp + (size_t)0 * ldw);
  wA1 = *(const float4*)(wp + (size_t)1 * ldw);
  wA2 = *(const float4*)(wp + (size_t)2 * ldw);
  wA3 = *(const float4*)(wp + (size_t)3 * ldw);
#pragma unroll 1
  for (int kk = 0; kk < K; kk += 8) {
    wB0 = *(const float4*)(wp + (size_t)(kk + 4) * ldw);
    wB1 = *(const float4*)(wp + (size_t)(kk + 5) * ldw);
    wB2 = *(const float4*)(wp + (size_t)(kk + 6) * ldw);
    wB3 = *(const float4*)(wp + (size_t)(kk + 7) * ldw);
    fma4<R>(acc, in, ro, kk, wA0, wA1, wA2, wA3);
    if (kk + 8 < K) {
      wA0 = *(const float4*)(wp + (size_t)(kk +  8) * ldw);
      wA1 = *(const float4*)(wp + (size_t)(kk +  9) * ldw);
      wA2 = *(const float4*)(wp + (size_t)(kk + 10) * ldw);
      wA3 = *(const float4*)(wp + (size_t)(kk + 11) * ldw);
    }
    fma4<R>(acc, in, ro, kk + 4, wB0, wB1, wB2, wB3);
  }
#pragma unroll
  for (int i = 0; i < R; ++i) {
    if (rb + i < T) {
      float4 r2 = acc[i];
      if (relu) {
        r2.x = fmaxf(r2.x, 0.f); r2.y = fmaxf(r2.y, 0.f);
        r2.z = fmaxf(r2.z, 0.f); r2.w = fmaxf(r2.w, 0.f);
      }
      *(float4*)(op + (rb + i) * ldo) = r2;
    }
  }
}

// out[0..128) = bias + in(1xK) @ W(Kx128). K sliced 8-way, LDS-reduced. 2 barriers.
__device__ inline void matvec128(const float* __restrict__ in, const float* __restrict__ W,
                                 const float* __restrict__ bias, float* __restrict__ out,
                                 int K, float* __restrict__ red, int tid)
{
  const int c = tid & 127;
  const int s = tid >> 7;      // 0..7
  const int ks = K >> 3;
  const int k0 = s * ks;
  float acc = 0.f;
#pragma unroll 8
  for (int k = k0; k < k0 + ks; ++k) acc = fmaf(in[k], W[(size_t)k * 128 + c], acc);
  red[tid] = acc;
  __syncthreads();
  if (tid < 128) {
    float sum = ((red[c] + red[128 + c]) + (red[256 + c] + red[384 + c]))
              + ((red[512 + c] + red[640 + c]) + (red[768 + c] + red[896 + c]));
    out[c] = bias[c] + sum;
  }
  __syncthreads();
}

// h[r] = LN(h[r] + a1[r] (+ a2[r])). One wave per row.
__device__ inline void layernorm_add2(float* __restrict__ h, const float* __restrict__ a1,
                                      const float* __restrict__ a2,
                                      const float* __restrict__ g, const float* __restrict__ bta,
                                      int T, int tid)
{
  const int lane = tid & 63;
  const int wvl = tid >> 6;
  for (int r = wvl; r < T; r += NT / 64) {
    float v0 = h[r * DM + lane]      + a1[r * DM + lane];
    float v1 = h[r * DM + lane + 64] + a1[r * DM + lane + 64];
    if (a2) { v0 += a2[r * DM + lane]; v1 += a2[r * DM + lane + 64]; }
    float sum = v0 + v1;
    for (int off = 32; off; off >>= 1) sum += __shfl_xor(sum, off);
    float mu = sum * (1.0f / 128.0f);
    float d0 = v0 - mu, d1 = v1 - mu;
    float sq = d0 * d0 + d1 * d1;
    for (int off = 32; off; off >>= 1) sq += __shfl_xor(sq, off);
    float rs = 1.0f / sqrtf(sq * (1.0f / 128.0f) + 1e-5f);
    h[r * DM + lane]      = g[lane]      * d0 * rs + bta[lane];
    h[r * DM + lane + 64] = g[lane + 64] * d1 * rs + bta[lane + 64];
  }
}

// 2-layer post-LN transformer encoder, all NT threads. h: T x 128 LDS (output persists).
// scr: shared scratch. R/NG: row-tile / row-group count (NG = ceil(T/R)).
template<int T, int R, int NG>
__device__ void encode_block(float* __restrict__ h, float* __restrict__ scr,
                             const float* __restrict__ tok,
                             const float* __restrict__ embW, const float* __restrict__ embB,
                             const float* __restrict__ attnW, const float* __restrict__ attnB,
                             const float* __restrict__ W1, const float* __restrict__ b1,
                             const float* __restrict__ W2, const float* __restrict__ b2,
                             const float* __restrict__ ln, int tid)
{
  const int lane = tid & 63;
  const int wvl = tid >> 6;
  constexpr int TT = T * T;
  float* q = scr;
  float* k = scr + T * DM;
  float* v = scr + 2 * T * DM;
  float* s = scr + 3 * T * DM;      // 8*T*T
  // embedding: h = tok(Tx2) @ embW(2x128) + embB
  for (int idx = tid; idx < T * DM; idx += NT) {
    int r = idx >> 7, c = idx & 127;
    h[idx] = tok[2 * r] * embW[c] + tok[2 * r + 1] * embW[DM + c] + embB[c];
  }
  __syncthreads();
  for (int l = 0; l < 2; ++l) {
    const float* Wq = attnW + (size_t)(l * 4) * DM * DM;     // Wq,Wk,Wv,Wo contiguous
    const float* bq = attnB + (l * 4) * DM;                  // bq,bk,bv,bo contiguous
    // fused QKV (NM=3)
    matmul_blk<R, NG, 3, DM>(h, DM, Wq, DM, DM * DM, bq, q, DM, T * DM, T, false, tid, 0);
    __syncthreads();
    // scores s[hd][i][j] = (q_i,hd . k_j,hd) / 4  (all 8 heads)
    for (int idx = tid; idx < NHD * TT; idx += NT) {
      int hd = idx / TT; int rem = idx - hd * TT; int i = rem / T; int j = rem - i * T;
      const float4* q4 = (const float4*)(q + i * DM + hd * HDM);
      const float4* k4 = (const float4*)(k + j * DM + hd * HDM);
      float acc = 0.f;
#pragma unroll
      for (int d = 0; d < 4; ++d) {
        float4 qa = q4[d], ka = k4[d];
        acc += qa.x * ka.x + qa.y * ka.y + qa.z * ka.z + qa.w * ka.w;
      }
      s[idx] = acc * 0.25f;
    }
    __syncthreads();
    // row softmax
    for (int r = wvl; r < NHD * T; r += NT / 64) {
      float val = (lane < T) ? s[r * T + lane] : -INFINITY;
      float mx = val;
      for (int off = 32; off; off >>= 1) mx = fmaxf(mx, __shfl_xor(mx, off));
      float e = (lane < T) ? expf(val - mx) : 0.f;
      float sum = e;
      for (int off = 32; off; off >>= 1) sum += __shfl_xor(sum, off);
      if (lane < T) s[r * T + lane] = e / sum;
    }
    __syncthreads();
    // attn out -> q (q dead after scores)
    for (int idx = tid; idx < T * DM; idx += NT) {
      int i = idx >> 7, c = idx & 127; int hd = c >> 4;
      const float* ar = s + (hd * T + i) * T;
      float acc = 0.f;
#pragma unroll 4
      for (int j = 0; j < T; ++j) acc = fmaf(ar[j], v[j * DM + c], acc);
      q[idx] = acc;
    }
    __syncthreads();
    // Wo: q -> v (v dead), then h = LN(h + v)
    matmul_blk<R, NG, 1, DM>(q, DM, Wq + (size_t)3 * DM * DM, DM, 0, bq + 3 * DM,
                             v, DM, 0, T, false, tid, 0);
    __syncthreads();
    layernorm_add2(h, v, nullptr, ln + ((l * 2 + 0) * 2 + 0) * DM, ln + ((l * 2 + 0) * 2 + 1) * DM, T, tid);
    __syncthreads();
    // FF1 (NM=4): hidden = relu(h @ W1 + b1)   [overlaps q/k/v/s: all dead]
    const float* W1l = W1 + (size_t)l * DM * FFDIM;
    const float* b1l = b1 + l * FFDIM;
    const float* W2l = W2 + (size_t)l * FFDIM * DM;
    float* hidden = scr;                 // T*512
    float* ff2o   = scr + T * FFDIM;     // T*128
    float* ff2b   = ff2o + T * DM;       // T*128
    matmul_blk<R, NG, 4, DM>(h, DM, W1l, FFDIM, 128, b1l, hidden, FFDIM, 128, T, true, tid, 0);
    __syncthreads();
    // FF2: two parallel K-slices (k 0..255 -> ff2o with bias, k 256..511 -> ff2b zero-init)
    matmul_blk<R, NG, 1, 256>(hidden, FFDIM, W2l, DM, 0, b2 + l * DM,
                              ff2o, DM, 0, T, false, tid, 0);
    matmul_blk<R, NG, 1, 256>(hidden + 256, FFDIM, W2l + (size_t)256 * DM, DM, 0, nullptr,
                              ff2b, DM, 0, T, false, tid, 256);
    __syncthreads();
    layernorm_add2(h, ff2o, ff2b, ln + ((l * 2 + 1) * 2 + 0) * DM, ln + ((l * 2 + 1) * 2 + 1) * DM, T, tid);
    __syncthreads();
  }
}

__global__ __launch_bounds__(NT)
void tsp_kernel(Params p)
{
  const int b = blockIdx.x;
  const int tid = threadIdx.x;
  const int lane = tid & 63;
  const int wv = tid >> 6;

  extern __shared__ float sm[];
  float* hA  = sm + OFF_HA;
  float* hS  = sm + OFF_HS;
  float* scr = sm + OFF_SCR;

  __shared__ float xl[NN * 2];
  __shared__ int   maskS[NN];
  __shared__ int   knnS[KS];
  __shared__ int   validS[KA];
  __shared__ float d2S[NN];
  __shared__ float tokA[TA * 2];
  __shared__ float tokS[TS * 2];
  __shared__ int   lastS;
  __shared__ float logpS;

  // ---- init ----
  for (int i = tid; i < NN * 2; i += NT) xl[i] = p.x[b * NN * 2 + i];
  const int st = p.start[b];
  for (int i = tid; i < NN; i += NT) maskS[i] = (i != st) ? 1 : 0;
  if (tid == 0) {
    lastS = st; logpS = 0.f;
    p.out[b * NN] = (float)st;
  }
  __syncthreads();
  const float fx = xl[2 * st], fy = xl[2 * st + 1];

  for (int t = 0; t < NN - 1; ++t) {
    const int last = lastS;
    const float lx = xl[2 * last], ly = xl[2 * last + 1];

    // ---- squared distances, masked -> BIG (no FMA contraction: match np bit-exact) ----
    for (int j = tid; j < NN; j += NT) {
      float dx = __fsub_rn(xl[2 * j], lx);
      float dy = __fsub_rn(xl[2 * j + 1], ly);
      float dd = __fadd_rn(__fmul_rn(dx, dx), __fmul_rn(dy, dy));
      d2S[j] = maskS[j] ? dd : BIGF;
    }
    __syncthreads();

    // ---- stable top-KS (ascending d2, ties -> lowest index), wave 0 ----
    if (wv == 0) {
      float v = (lane < NN) ? d2S[lane] : 2.0f * BIGF;
      const int vi = lane;
      for (int s2 = 0; s2 < KS; ++s2) {
        float mv = v; int mi = vi;
        for (int off = 32; off; off >>= 1) {
          float ov = __shfl_xor(mv, off);
          int oi = __shfl_xor(mi, off);
          if (ov < mv || (ov == mv && oi < mi)) { mv = ov; mi = oi; }
        }
        if (lane == 0) knnS[s2] = mi;
        if (vi == mi) v = 4.0f * BIGF;  // remove winner
      }
    }
    __syncthreads();

    // ---- valid flags + tokens ----
    if (tid < KA) validS[tid] = maskS[knnS[tid]];
    if (tid < KS) { int j = knnS[tid]; tokS[2 * tid] = xl[2 * j]; tokS[2 * tid + 1] = xl[2 * j + 1]; }
    if (tid < KA) { int j = knnS[tid]; tokA[2 * tid] = xl[2 * j]; tokA[2 * tid + 1] = xl[2 * j + 1]; }
    if (tid == NT - 1) { tokA[2 * KA] = lx; tokA[2 * KA + 1] = ly; }
    if (tid == NT - 2) { tokS[2 * KS] = lx; tokS[2 * KS + 1] = ly; }
    if (tid == NT - 3) { tokS[2 * KS + 2] = fx; tokS[2 * KS + 3] = fy; }
    __syncthreads();

    // ---- encoder A (16 tokens, output in hA) then encoder S (37 tokens, in hS) ----
    encode_block<TA, 4, 4>(hA, scr, tokA, p.a_emb_W, p.a_emb_b, p.a_attn_W, p.a_attn_b,
                           p.a_ff_W1, p.a_ff_b1, p.a_ff_W2, p.a_ff_b2, p.a_ln, tid);
    encode_block<TS, 8, 5>(hS, scr, tokS, p.s_emb_W, p.s_emb_b, p.s_attn_W, p.s_attn_b,
                           p.s_ff_W1, p.s_ff_b1, p.s_ff_W2, p.s_ff_b2, p.s_ln, tid);

    // ---- decoder scratch in scr (encoder scratch dead; hA/hS persist) ----
    float* embq = scr;            // 384
    float* embo = scr + 384;      // 15 x 256
    float* Kd   = scr + 4224;     // 15 x 256
    float* Vd   = scr + 8064;     // 15 x 256
    float* hdec = scr + 11904;    // 128
    float* qd   = scr + 12032;    // 128
    float* scd  = scr + 12160;    // 8 x 15 = 120
    float* od   = scr + 12288;    // 128
    float* tmp  = scr + 12416;    // 128
    float* red  = scr + 12544;    // 1024

    if (tid < 384) {
      embq[tid] = (tid < 128) ? hA[KA * DM + tid]
                : (tid < 256) ? hS[KS * DM + (tid - 128)]
                              : hS[(KS + 1) * DM + (tid - 256)];
    }
    for (int idx = tid; idx < KA * 256; idx += NT) {
      int r = idx >> 8, c = idx & 255;
      embo[idx] = (c < 128) ? hA[r * DM + c] : hS[r * DM + (c - 128)];
    }
    __syncthreads();

    // K/V: 15x256 = embo(15x256) @ WK/WV(256x256); NM=2 blocks, parallel thread windows
    matmul_blk<8, 2, 2, 256>(embo, 256, p.WK, 256, 128, p.bK, Kd, 256, 128, KA, false, tid, 0);
    matmul_blk<8, 2, 2, 256>(embo, 256, p.WV, 256, 128, p.bV, Vd, 256, 128, KA, false, tid, 128);
    matvec128(embq, p.Wq_mlp, p.bq_mlp, hdec, 384, red, tid);  // internal syncs cover K/V too

    // ---- decoder layer 0 (cross-attention) ----
    matvec128(hdec, p.d_Wq, p.d_bq, qd, DM, red, tid);
    if (tid < NHD * KA) {   // 120 threads
      int hd = tid / KA, kk2 = tid - hd * KA;
      const float* qh = qd + hd * HDM;
      const float* kh = Kd + kk2 * 256 + hd * HDM;
      float acc = 0.f;
#pragma unroll
      for (int d = 0; d < HDM; ++d) acc += qh[d] * kh[d];
      acc = acc / 4.0f;
      scd[tid] = validS[kk2] ? acc : -BIGF;
    }
    __syncthreads();
    if (tid < NHD) {
      float mx = -INFINITY;
#pragma unroll
      for (int kk2 = 0; kk2 < KA; ++kk2) mx = fmaxf(mx, scd[tid * KA + kk2]);
      float e[KA]; float sum = 0.f;
#pragma unroll
      for (int kk2 = 0; kk2 < KA; ++kk2) { e[kk2] = expf(scd[tid * KA + kk2] - mx); sum += e[kk2]; }
      float inv = 1.0f / sum;
#pragma unroll
      for (int kk2 = 0; kk2 < KA; ++kk2) scd[tid * KA + kk2] = e[kk2] * inv;
    }
    __syncthreads();
    if (tid < DM) {
      int hd = tid >> 4;
      float acc = 0.f;
#pragma unroll
      for (int kk2 = 0; kk2 < KA; ++kk2) acc = fmaf(scd[hd * KA + kk2], Vd[kk2 * 256 + tid], acc);
      od[tid] = acc;
    }
    __syncthreads();
    matvec128(od, p.d_Wo, p.d_bo, tmp, DM, red, tid);
    if (tid < DM) hdec[tid] += tmp[tid];
    __syncthreads();

    // ---- final pointer logits ----
    matvec128(hdec, p.d_Wq + DM * DM, p.d_bq + DM, qd, DM, red, tid);
    if (wv == 0) {
      float lg = -BIGF;
      if (lane < KA) {
        const float* kf = Kd + lane * 256 + 128;  // K[:, :, 1]
        float acc = 0.f;
#pragma unroll 8
        for (int d = 0; d < DM; ++d) acc = fmaf(qd[d], kf[d], acc);
        acc = acc / 11.313708498984761f;  // sqrt(128)
        lg = validS[lane] ? 10.0f * tanhf(acc) : -BIGF;
      }
      // argmax, ties -> lowest index (== argmax of softmax probs)
      float mv = lg; int mi = (lane < KA) ? lane : 1000;
      for (int off = 32; off; off >>= 1) {
        float ov = __shfl_xor(mv, off);
        int oi = __shfl_xor(mi, off);
        if (ov > mv || (ov == mv && oi < mi)) { mv = ov; mi = oi; }
      }
      float e = (lane < KA) ? expf(lg - mv) : 0.f;
      float sum = e;
      for (int off = 32; off; off >>= 1) sum += __shfl_xor(sum, off);
      if (lane == 0) {
        int nxt = knnS[mi];
        logpS += -logf(sum);  // lg[mi] - mv == 0
        maskS[nxt] = 0;
        lastS = nxt;
        p.out[b * NN + t + 1] = (float)nxt;
      }
    }
    __syncthreads();
  }

  if (tid == 0) p.out[NB * NN + b] = logpS;
}

} // namespace

extern "C" void kernel_launch(void* const* d_in, const int* in_sizes, int n_in,
                              void* d_out, int out_size, void* d_ws, size_t ws_size,
                              hipStream_t stream)
{
  (void)in_sizes; (void)n_in; (void)out_size; (void)d_ws; (void)ws_size;
  Params p;
  p.x        = (const float*)d_in[0];
  p.start    = (const int*)d_in[1];
  // d_in[2]=action_k (15), d_in[3]=state_k (35): fixed by problem, hardcoded.
  p.a_emb_W  = (const float*)d_in[4];
  p.a_emb_b  = (const float*)d_in[5];
  p.a_attn_W = (const float*)d_in[6];
  p.a_attn_b = (const float*)d_in[7];
  p.a_ff_W1  = (const float*)d_in[8];
  p.a_ff_b1  = (const float*)d_in[9];
  p.a_ff_W2  = (const float*)d_in[10];
  p.a_ff_b2  = (const float*)d_in[11];
  p.a_ln     = (const float*)d_in[12];
  p.s_emb_W  = (const float*)d_in[13];
  p.s_emb_b  = (const float*)d_in[14];
  p.s_attn_W = (const float*)d_in[15];
  p.s_attn_b = (const float*)d_in[16];
  p.s_ff_W1  = (const float*)d_in[17];
  p.s_ff_b1  = (const float*)d_in[18];
  p.s_ff_W2  = (const float*)d_in[19];
  p.s_ff_b2  = (const float*)d_in[20];
  p.s_ln     = (const float*)d_in[21];
  p.WK       = (const float*)d_in[22];
  p.bK       = (const float*)d_in[23];
  p.WV       = (const float*)d_in[24];
  p.bV       = (const float*)d_in[25];
  p.Wq_mlp   = (const float*)d_in[26];
  p.bq_mlp   = (const float*)d_in[27];
  p.d_Wq     = (const float*)d_in[28];
  p.d_bq     = (const float*)d_in[29];
  p.d_Wo     = (const float*)d_in[30];
  p.d_bo     = (const float*)d_in[31];
  p.out      = (float*)d_out;

  (void)hipFuncSetAttribute((const void*)tsp_kernel,
                            hipFuncAttributeMaxDynamicSharedMemorySize, SMEM_BYTES);
  tsp_kernel<<<NB, NT, SMEM_BYTES, stream>>>(p);
}